// Round 2
// baseline (201.561 us; speedup 1.0000x reference)
//
#include <hip/hip_runtime.h>

#define DEVINL __device__ __forceinline__

typedef __attribute__((ext_vector_type(4))) float f32x4;
typedef __attribute__((ext_vector_type(8))) short short8;

constexpr int kBN = 12, kC = 256, kH = 40, kW = 100;
constexpr int kNQ = kH * kW;      // 4000
constexpr int kM = kBN * kNQ;     // 48000

DEVINL float bflo(uint p) { union { uint i; float f; } v; v.i = p << 16; return v.f; }
DEVINL float bfhi(uint p) { union { uint i; float f; } v; v.i = p & 0xffff0000u; return v.f; }
DEVINL ushort f2bf(float f) {
  union { float f; uint i; } v; v.f = f;
  uint i = v.i;
  return (ushort)((i + 0x7fffu + ((i >> 16) & 1u)) >> 16);  // RNE
}
DEVINL uint pack2(float a, float b) { return (uint)f2bf(a) | ((uint)f2bf(b) << 16); }

DEVINL void mfma_bf16(f32x4& acc, short8 a, short8 b) {
  acc = __builtin_amdgcn_mfma_f32_16x16x32_bf16(a, b, acc, 0, 0, 0);
}

DEVINL void acc8(float* acc, uint4 d, float wv) {
  acc[0] += wv * bflo(d.x); acc[1] += wv * bfhi(d.x);
  acc[2] += wv * bflo(d.y); acc[3] += wv * bfhi(d.y);
  acc[4] += wv * bflo(d.z); acc[5] += wv * bfhi(d.z);
  acc[6] += wv * bflo(d.w); acc[7] += wv * bfhi(d.w);
}

// ---------------- K0: weight transpose + bf16 convert: W[K][N] -> WT[N][K] ----
__global__ __launch_bounds__(256) void k_wt(const float* __restrict__ W,
                                            ushort* __restrict__ WT, int K, int N) {
  int idx = blockIdx.x * 256 + threadIdx.x;
  if (idx >= K * N) return;
  int n = idx / K, k = idx - n * K;
  WT[idx] = f2bf(W[k * N + n]);
}

// ---------------- K1: img NCHW f32 -> feat [b][q][c] bf16 --------------------
__global__ __launch_bounds__(256) void k_transpose(const float* __restrict__ img,
                                                   ushort* __restrict__ feat) {
  __shared__ ushort tile[64][66];
  int b = blockIdx.z, c0 = blockIdx.y * 64, q0 = blockIdx.x * 64;
  int t = threadIdx.x;
  int ql = t & 63, cl = t >> 6;
#pragma unroll
  for (int i = 0; i < 16; ++i) {
    int c = cl + i * 4, q = q0 + ql;
    float v = (q < kNQ) ? img[(size_t)(b * kC + c0 + c) * kNQ + q] : 0.f;
    tile[c][ql] = f2bf(v);
  }
  __syncthreads();
  int cc = t & 63, qr = t >> 6;
#pragma unroll
  for (int i = 0; i < 16; ++i) {
    int qlo = qr + i * 4, q = q0 + qlo;
    if (q < kNQ) feat[(size_t)(b * kNQ + q) * kC + c0 + cc] = tile[cc][qlo];
  }
}

// ---------------- K2: BEV warp: bilinear(feat, grid) -> warped bf16 ----------
__global__ __launch_bounds__(256) void k_warp(const ushort* __restrict__ feat,
                                              const float* __restrict__ grid,
                                              ushort* __restrict__ warped) {
  int b = blockIdx.y;
  int t = threadIdx.x;
  int q = blockIdx.x * 32 + (t >> 3), g = t & 7;
  float gx = grid[(size_t)(b * kNQ + q) * 2 + 0] * kW - 0.5f;
  float gy = grid[(size_t)(b * kNQ + q) * 2 + 1] * kH - 0.5f;
  float x0f = floorf(gx), y0f = floorf(gy);
  int x0 = (int)x0f, y0 = (int)y0f;
  float wx = gx - x0f, wy = gy - y0f;
  float acc[32];
#pragma unroll
  for (int i = 0; i < 32; ++i) acc[i] = 0.f;
  int c0 = g * 32;
#pragma unroll
  for (int ty = 0; ty < 2; ++ty) {
    int iy = y0 + ty;
    if (iy < 0 || iy >= kH) continue;
    float wyv = ty ? wy : 1.f - wy;
#pragma unroll
    for (int tx = 0; tx < 2; ++tx) {
      int ix = x0 + tx;
      if (ix < 0 || ix >= kW) continue;
      float wv = wyv * (tx ? wx : 1.f - wx);
      const uint4* src = (const uint4*)(feat + (size_t)(b * kNQ + iy * kW + ix) * kC + c0);
#pragma unroll
      for (int i = 0; i < 4; ++i) acc8(acc + i * 8, src[i], wv);
    }
  }
  uint o[16];
#pragma unroll
  for (int i = 0; i < 16; ++i) o[i] = pack2(acc[2 * i], acc[2 * i + 1]);
  uint4* dst = (uint4*)(warped + (size_t)(b * kNQ + q) * kC + c0);
#pragma unroll
  for (int i = 0; i < 4; ++i) dst[i] = ((uint4*)o)[i];
}

// ---------------- K3/K6: MFMA GEMM, M-tile 32, N=256, K=256 ------------------
// A [M][256] bf16 row-major, BT [256][256] bf16 (pre-transposed weights [N][K]).
// EPI 0: store bf16 (acc + bias)  -> Obf [M][256]
// EPI 1: out NCHW fp32: acc + bias[col] + resid, via LDS transpose
template <int EPI>
__global__ __launch_bounds__(256) void k_gemm256(const ushort* __restrict__ A,
                                                 const ushort* __restrict__ BT,
                                                 const float* __restrict__ bias,
                                                 ushort* __restrict__ Obf,
                                                 float* __restrict__ Ofp,
                                                 const float* __restrict__ resid) {
  extern __shared__ char smem[];
  ushort* As = (ushort*)smem;           // [32][32] bf16, 64B rows, XOR-swizzled
  ushort* Bs = (ushort*)(smem + 2048);  // [256][32]
  const int t = threadIdx.x, wave = t >> 6, lane = t & 63;
  const int l15 = lane & 15, l4 = lane >> 4;
  const int m0 = blockIdx.x * 32;
  const int n0w = wave * 64;
  f32x4 acc[2][4];
#pragma unroll
  for (int i = 0; i < 2; ++i)
#pragma unroll
    for (int j = 0; j < 4; ++j) acc[i][j] = (f32x4)0.f;

  for (int kk = 0; kk < 256; kk += 32) {
    if (t < 128) {
      int r = t >> 2, ch = t & 3;
      uint4 d = *(const uint4*)(A + (size_t)(m0 + r) * 256 + kk + ch * 8);
      *(uint4*)((char*)As + r * 64 + ((ch * 16) ^ ((r & 3) << 4))) = d;
    }
#pragma unroll
    for (int i = 0; i < 4; ++i) {
      int idx = t + i * 256;
      int r = idx >> 2, ch = idx & 3;
      uint4 d = *(const uint4*)(BT + (size_t)r * 256 + kk + ch * 8);
      *(uint4*)((char*)Bs + r * 64 + ((ch * 16) ^ ((r & 3) << 4))) = d;
    }
    __syncthreads();
    short8 a[2], bfr[4];
#pragma unroll
    for (int mf = 0; mf < 2; ++mf) {
      int r = mf * 16 + l15;
      a[mf] = *(const short8*)((char*)As + r * 64 + ((l4 * 16) ^ ((r & 3) << 4)));
    }
#pragma unroll
    for (int nf = 0; nf < 4; ++nf) {
      int r = n0w + nf * 16 + l15;
      bfr[nf] = *(const short8*)((char*)Bs + r * 64 + ((l4 * 16) ^ ((r & 3) << 4)));
    }
#pragma unroll
    for (int mf = 0; mf < 2; ++mf)
#pragma unroll
      for (int nf = 0; nf < 4; ++nf) mfma_bf16(acc[mf][nf], a[mf], bfr[nf]);
    __syncthreads();
  }

  if (EPI == 0) {
#pragma unroll
    for (int mf = 0; mf < 2; ++mf)
#pragma unroll
      for (int nf = 0; nf < 4; ++nf) {
        int col = n0w + nf * 16 + l15;
        float bv = bias[col];
#pragma unroll
        for (int j = 0; j < 4; ++j) {
          int row = m0 + mf * 16 + l4 * 4 + j;
          Obf[(size_t)row * 256 + col] = f2bf(acc[mf][nf][j] + bv);
        }
      }
  } else {
    float* T = (float*)smem;  // [256][33] fp32 (aliases As/Bs, dead after loop)
#pragma unroll
    for (int mf = 0; mf < 2; ++mf)
#pragma unroll
      for (int nf = 0; nf < 4; ++nf) {
        int col = n0w + nf * 16 + l15;
        float bv = bias[col];
#pragma unroll
        for (int j = 0; j < 4; ++j) {
          int rl = mf * 16 + l4 * 4 + j;
          T[col * 33 + rl] = acc[mf][nf][j] + bv;
        }
      }
    __syncthreads();
    int b = m0 / kNQ, q0 = m0 % kNQ;
    int qv = t & 31, cr = t >> 5;
#pragma unroll
    for (int i = 0; i < 32; ++i) {
      int c = cr + i * 8;
      size_t gi = (size_t)(b * kC + c) * kNQ + q0 + qv;
      Ofp[gi] = T[c * 33 + qv] + resid[gi];
    }
  }
}

// ---------------- K4: off+attn GEMM (N=96) + softmax + coord epilogue --------
__global__ __launch_bounds__(256) void k_offattn(const ushort* __restrict__ A,
                                                 const ushort* __restrict__ WoffT,
                                                 const ushort* __restrict__ WattnT,
                                                 const float* __restrict__ boff,
                                                 const float* __restrict__ battn,
                                                 const float* __restrict__ refp,
                                                 float4* __restrict__ samp) {
  __shared__ ushort As[32 * 32];
  __shared__ ushort Bs[96 * 32];
  __shared__ float T[32 * 100];
  const int t = threadIdx.x, wave = t >> 6, lane = t & 63;
  const int l15 = lane & 15, l4 = lane >> 4;
  const int m0 = blockIdx.x * 32;
  const int mf = wave & 1, nbase = (wave >> 1) * 48;
  f32x4 acc[3] = {(f32x4)0.f, (f32x4)0.f, (f32x4)0.f};

  for (int kk = 0; kk < 256; kk += 32) {
    if (t < 128) {
      int r = t >> 2, ch = t & 3;
      uint4 d = *(const uint4*)(A + (size_t)(m0 + r) * 256 + kk + ch * 8);
      *(uint4*)((char*)As + r * 64 + ((ch * 16) ^ ((r & 3) << 4))) = d;
    }
#pragma unroll
    for (int i = 0; i < 2; ++i) {
      int id = t + i * 256;
      if (id < 384) {
        int r = id >> 2, ch = id & 3;
        const ushort* src = (r < 64) ? (WoffT + (size_t)r * 256) : (WattnT + (size_t)(r - 64) * 256);
        uint4 d = *(const uint4*)(src + kk + ch * 8);
        *(uint4*)((char*)Bs + r * 64 + ((ch * 16) ^ ((r & 3) << 4))) = d;
      }
    }
    __syncthreads();
    short8 a;
    {
      int r = mf * 16 + l15;
      a = *(const short8*)((char*)As + r * 64 + ((l4 * 16) ^ ((r & 3) << 4)));
    }
#pragma unroll
    for (int nf = 0; nf < 3; ++nf) {
      int r = nbase + nf * 16 + l15;
      short8 bb = *(const short8*)((char*)Bs + r * 64 + ((l4 * 16) ^ ((r & 3) << 4)));
      mfma_bf16(acc[nf], a, bb);
    }
    __syncthreads();
  }
#pragma unroll
  for (int nf = 0; nf < 3; ++nf) {
    int col = nbase + nf * 16 + l15;
    float bv = (col < 64) ? boff[col] : battn[col - 64];
#pragma unroll
    for (int j = 0; j < 4; ++j) {
      int rl = mf * 16 + l4 * 4 + j;
      T[rl * 100 + col] = acc[nf][j] + bv;
    }
  }
  __syncthreads();
  int ql = t >> 3, h = t & 7;
  int b = m0 / kNQ, q = m0 % kNQ + ql;
  float refx = refp[(size_t)(b * kNQ + q) * 2 + 0] * kW - 0.5f;
  float refy = refp[(size_t)(b * kNQ + q) * 2 + 1] * kH - 0.5f;
  float sx[4], sy[4], lg[4];
#pragma unroll
  for (int p = 0; p < 4; ++p) {
    sx[p] = refx + T[ql * 100 + h * 8 + p * 2 + 0];
    sy[p] = refy + T[ql * 100 + h * 8 + p * 2 + 1];
    lg[p] = T[ql * 100 + 64 + h * 4 + p];
  }
  float mx = fmaxf(fmaxf(lg[0], lg[1]), fmaxf(lg[2], lg[3]));
  float e[4], s = 0.f;
#pragma unroll
  for (int p = 0; p < 4; ++p) { e[p] = __expf(lg[p] - mx); s += e[p]; }
  float inv = 1.f / s;
  float4* dst = samp + (size_t)(b * kNQ + q) * 32 + h * 4;
#pragma unroll
  for (int p = 0; p < 4; ++p) dst[p] = make_float4(sx[p], sy[p], e[p] * inv, 0.f);
}

// ---------------- K5: deformable sampling + attention aggregate --------------
__global__ __launch_bounds__(256) void k_sample(const ushort* __restrict__ v,
                                                const float4* __restrict__ samp,
                                                ushort* __restrict__ agg) {
  int b = blockIdx.y;
  int t = threadIdx.x;
  int q = blockIdx.x * 32 + (t >> 3), h = t & 7;
  const float4* sp = samp + (size_t)(b * kNQ + q) * 32 + h * 4;
  float acc[32];
#pragma unroll
  for (int i = 0; i < 32; ++i) acc[i] = 0.f;
#pragma unroll
  for (int p = 0; p < 4; ++p) {
    float4 s = sp[p];
    float x0f = floorf(s.x), y0f = floorf(s.y);
    int x0 = (int)x0f, y0 = (int)y0f;
    float wx = s.x - x0f, wy = s.y - y0f;
#pragma unroll
    for (int ty = 0; ty < 2; ++ty) {
      int iy = y0 + ty;
      if (iy < 0 || iy >= kH) continue;
      float wyv = ty ? wy : 1.f - wy;
#pragma unroll
      for (int tx = 0; tx < 2; ++tx) {
        int ix = x0 + tx;
        if (ix < 0 || ix >= kW) continue;
        float wv = s.z * wyv * (tx ? wx : 1.f - wx);
        const uint4* src = (const uint4*)(v + (size_t)(b * kNQ + iy * kW + ix) * kC + h * 32);
#pragma unroll
        for (int i = 0; i < 4; ++i) acc8(acc + i * 8, src[i], wv);
      }
    }
  }
  uint o[16];
#pragma unroll
  for (int i = 0; i < 16; ++i) o[i] = pack2(acc[2 * i], acc[2 * i + 1]);
  uint4* dst = (uint4*)(agg + (size_t)(b * kNQ + q) * kC + h * 32);
#pragma unroll
  for (int i = 0; i < 4; ++i) dst[i] = ((uint4*)o)[i];
}

extern "C" void kernel_launch(void* const* d_in, const int* in_sizes, int n_in,
                              void* d_out, int out_size, void* d_ws, size_t ws_size,
                              hipStream_t stream) {
  const float* img   = (const float*)d_in[0];
  const float* grid  = (const float*)d_in[1];
  const float* refp  = (const float*)d_in[2];
  const float* Wv    = (const float*)d_in[3];
  const float* bv    = (const float*)d_in[4];
  const float* Woff  = (const float*)d_in[5];
  const float* boff  = (const float*)d_in[6];
  const float* Wattn = (const float*)d_in[7];
  const float* battn = (const float*)d_in[8];
  const float* Wout  = (const float*)d_in[9];
  const float* bout  = (const float*)d_in[10];
  float* out = (float*)d_out;

  char* ws = (char*)d_ws;
  const size_t SZ = (size_t)kM * kC * 2;  // 24.576 MB per bf16 [M][C] buffer
  ushort* feat   = (ushort*)(ws);
  ushort* warped = (ushort*)(ws + SZ);
  ushort* vbuf   = (ushort*)(ws + 2 * SZ);
  float4* samp   = (float4*)(ws + 3 * SZ);            // 24.576 MB
  ushort* WvT    = (ushort*)(ws + 4 * SZ);
  ushort* WoffT  = (ushort*)(ws + 4 * SZ + 131072);
  ushort* WattnT = (ushort*)(ws + 4 * SZ + 131072 + 32768);
  ushort* WoutT  = (ushort*)(ws + 4 * SZ + 131072 + 32768 + 16384);
  ushort* aggb   = warped;  // warped is dead after K3; reuse for agg

  k_wt<<<(65536 + 255) / 256, 256, 0, stream>>>(Wv, WvT, 256, 256);
  k_wt<<<(16384 + 255) / 256, 256, 0, stream>>>(Woff, WoffT, 256, 64);
  k_wt<<<(8192 + 255) / 256, 256, 0, stream>>>(Wattn, WattnT, 256, 32);
  k_wt<<<(65536 + 255) / 256, 256, 0, stream>>>(Wout, WoutT, 256, 256);

  k_transpose<<<dim3(63, 4, 12), 256, 0, stream>>>(img, feat);
  k_warp<<<dim3(125, 12), 256, 0, stream>>>(feat, grid, warped);
  k_gemm256<0><<<kM / 32, 256, 18432, stream>>>(warped, WvT, bv, vbuf, nullptr, nullptr);
  k_offattn<<<kM / 32, 256, 0, stream>>>(feat, WoffT, WattnT, boff, battn, refp, samp);
  k_sample<<<dim3(125, 12), 256, 0, stream>>>(vbuf, samp, aggb);
  k_gemm256<1><<<kM / 32, 256, 33792, stream>>>(aggb, WoutT, bout, nullptr, out, img);
}

// Round 5
// 162.377 us; speedup vs baseline: 1.2413x; 1.2413x over previous
//
#include <hip/hip_runtime.h>

#define DEVINL __device__ __forceinline__

typedef __attribute__((ext_vector_type(4))) float f32x4;
typedef __attribute__((ext_vector_type(8))) short short8;

constexpr int kBN = 12, kC = 256, kH = 40, kW = 100;
constexpr int kNQ = kH * kW;      // 4000
constexpr int kM = kBN * kNQ;     // 48000

DEVINL float bflo(uint p) { union { uint i; float f; } v; v.i = p << 16; return v.f; }
DEVINL float bfhi(uint p) { union { uint i; float f; } v; v.i = p & 0xffff0000u; return v.f; }
DEVINL ushort f2bf(float f) {
  union { float f; uint i; } v; v.f = f;
  uint i = v.i;
  return (ushort)((i + 0x7fffu + ((i >> 16) & 1u)) >> 16);  // RNE
}
DEVINL uint pack2(float a, float b) { return (uint)f2bf(a) | ((uint)f2bf(b) << 16); }

DEVINL void mfma_bf16(f32x4& acc, short8 a, short8 b) {
  acc = __builtin_amdgcn_mfma_f32_16x16x32_bf16(a, b, acc, 0, 0, 0);
}

DEVINL void acc8(float* acc, uint4 d, float wv) {
  acc[0] += wv * bflo(d.x); acc[1] += wv * bfhi(d.x);
  acc[2] += wv * bflo(d.y); acc[3] += wv * bfhi(d.y);
  acc[4] += wv * bflo(d.z); acc[5] += wv * bfhi(d.z);
  acc[6] += wv * bflo(d.w); acc[7] += wv * bfhi(d.w);
}

// ---------------- K0: weight transpose + bf16 convert: W[K][N] -> WT[N][K] ----
__global__ __launch_bounds__(256) void k_wt(const float* __restrict__ W,
                                            ushort* __restrict__ WT, int K, int N) {
  int idx = blockIdx.x * 256 + threadIdx.x;
  if (idx >= K * N) return;
  int n = idx / K, k = idx - n * K;
  WT[idx] = f2bf(W[k * N + n]);
}

// ---------------- K1: img NCHW f32 -> feat [b][q][c] bf16 --------------------
__global__ __launch_bounds__(256) void k_transpose(const float* __restrict__ img,
                                                   ushort* __restrict__ feat) {
  __shared__ ushort tile[64][66];
  int b = blockIdx.z, c0 = blockIdx.y * 64, q0 = blockIdx.x * 64;
  int t = threadIdx.x;
  int ql = t & 63, cl = t >> 6;
#pragma unroll
  for (int i = 0; i < 16; ++i) {
    int c = cl + i * 4, q = q0 + ql;
    float v = (q < kNQ) ? img[(size_t)(b * kC + c0 + c) * kNQ + q] : 0.f;
    tile[c][ql] = f2bf(v);
  }
  __syncthreads();
  int cc = t & 63, qr = t >> 6;
#pragma unroll
  for (int i = 0; i < 16; ++i) {
    int qlo = qr + i * 4, q = q0 + qlo;
    if (q < kNQ) feat[(size_t)(b * kNQ + q) * kC + c0 + cc] = tile[cc][qlo];
  }
}

// ---------------- K2: BEV warp: bilinear(feat, grid) -> warped bf16 ----------
// 1D grid of 1500 blocks, bijective XCD swizzle so each XCD works ~1.5 b-slabs
// (feat slab per b = 2 MB; XCD working set ~3 MB <= 4 MB L2).
__global__ __launch_bounds__(256) void k_warp(const ushort* __restrict__ feat,
                                              const float* __restrict__ grid,
                                              ushort* __restrict__ warped) {
  // bijective swizzle, nwg=1500: Q=187, R=4
  int orig = blockIdx.x;
  int xcd = orig & 7, i = orig >> 3;
  int n = (xcd < 4 ? xcd * 188 : 4 * 188 + (xcd - 4) * 187) + i;
  int b = n / 125, qc = n - b * 125;
  int t = threadIdx.x;
  int q = qc * 32 + (t >> 3), g = t & 7;
  float gx = grid[(size_t)(b * kNQ + q) * 2 + 0] * kW - 0.5f;
  float gy = grid[(size_t)(b * kNQ + q) * 2 + 1] * kH - 0.5f;
  float x0f = floorf(gx), y0f = floorf(gy);
  int x0 = (int)x0f, y0 = (int)y0f;
  float wx = gx - x0f, wy = gy - y0f;
  float acc[32];
#pragma unroll
  for (int i2 = 0; i2 < 32; ++i2) acc[i2] = 0.f;
  int c0 = g * 32;
#pragma unroll
  for (int ty = 0; ty < 2; ++ty) {
    int iy = y0 + ty;
    if (iy < 0 || iy >= kH) continue;
    float wyv = ty ? wy : 1.f - wy;
#pragma unroll
    for (int tx = 0; tx < 2; ++tx) {
      int ix = x0 + tx;
      if (ix < 0 || ix >= kW) continue;
      float wv = wyv * (tx ? wx : 1.f - wx);
      const uint4* src = (const uint4*)(feat + (size_t)(b * kNQ + iy * kW + ix) * kC + c0);
#pragma unroll
      for (int i2 = 0; i2 < 4; ++i2) acc8(acc + i2 * 8, src[i2], wv);
    }
  }
  uint o[16];
#pragma unroll
  for (int i2 = 0; i2 < 16; ++i2) o[i2] = pack2(acc[2 * i2], acc[2 * i2 + 1]);
  uint4* dst = (uint4*)(warped + (size_t)(b * kNQ + q) * kC + c0);
#pragma unroll
  for (int i2 = 0; i2 < 4; ++i2) dst[i2] = ((uint4*)o)[i2];
}

// ---------------- K3/K6: MFMA GEMM, M-tile 32, N=256, K=256 ------------------
// A [M][256] bf16 row-major, BT [256][256] bf16 (pre-transposed weights [N][K]).
// EPI 0: v store, HEAD-MAJOR: vbuf[((b*8+h)*kNQ + q)*32 + ch]   (bf16)
// EPI 1: out NCHW fp32: acc + bias[col] + resid, via LDS transpose
template <int EPI>
__global__ __launch_bounds__(256) void k_gemm256(const ushort* __restrict__ A,
                                                 const ushort* __restrict__ BT,
                                                 const float* __restrict__ bias,
                                                 ushort* __restrict__ Obf,
                                                 float* __restrict__ Ofp,
                                                 const float* __restrict__ resid) {
  extern __shared__ char smem[];
  ushort* As = (ushort*)smem;           // [32][32] bf16, 64B rows, XOR-swizzled
  ushort* Bs = (ushort*)(smem + 2048);  // [256][32]
  const int t = threadIdx.x, wave = t >> 6, lane = t & 63;
  const int l15 = lane & 15, l4 = lane >> 4;
  const int m0 = blockIdx.x * 32;
  const int n0w = wave * 64;
  f32x4 acc[2][4];
#pragma unroll
  for (int i = 0; i < 2; ++i)
#pragma unroll
    for (int j = 0; j < 4; ++j) acc[i][j] = (f32x4)0.f;

  for (int kk = 0; kk < 256; kk += 32) {
    if (t < 128) {
      int r = t >> 2, ch = t & 3;
      uint4 d = *(const uint4*)(A + (size_t)(m0 + r) * 256 + kk + ch * 8);
      *(uint4*)((char*)As + r * 64 + ((ch * 16) ^ ((r & 3) << 4))) = d;
    }
#pragma unroll
    for (int i = 0; i < 4; ++i) {
      int idx = t + i * 256;
      int r = idx >> 2, ch = idx & 3;
      uint4 d = *(const uint4*)(BT + (size_t)r * 256 + kk + ch * 8);
      *(uint4*)((char*)Bs + r * 64 + ((ch * 16) ^ ((r & 3) << 4))) = d;
    }
    __syncthreads();
    short8 a[2], bfr[4];
#pragma unroll
    for (int mf = 0; mf < 2; ++mf) {
      int r = mf * 16 + l15;
      a[mf] = *(const short8*)((char*)As + r * 64 + ((l4 * 16) ^ ((r & 3) << 4)));
    }
#pragma unroll
    for (int nf = 0; nf < 4; ++nf) {
      int r = n0w + nf * 16 + l15;
      bfr[nf] = *(const short8*)((char*)Bs + r * 64 + ((l4 * 16) ^ ((r & 3) << 4)));
    }
#pragma unroll
    for (int mf = 0; mf < 2; ++mf)
#pragma unroll
      for (int nf = 0; nf < 4; ++nf) mfma_bf16(acc[mf][nf], a[mf], bfr[nf]);
    __syncthreads();
  }

  if (EPI == 0) {
    int b = m0 / kNQ, q0 = m0 % kNQ;
#pragma unroll
    for (int mf = 0; mf < 2; ++mf)
#pragma unroll
      for (int nf = 0; nf < 4; ++nf) {
        int col = n0w + nf * 16 + l15;
        float bv = bias[col];
        int h = col >> 5, ch = col & 31;
#pragma unroll
        for (int j = 0; j < 4; ++j) {
          int q = q0 + mf * 16 + l4 * 4 + j;
          Obf[((size_t)(b * 8 + h) * kNQ + q) * 32 + ch] = f2bf(acc[mf][nf][j] + bv);
        }
      }
  } else {
    float* T = (float*)smem;  // [256][33] fp32 (aliases As/Bs, dead after loop)
#pragma unroll
    for (int mf = 0; mf < 2; ++mf)
#pragma unroll
      for (int nf = 0; nf < 4; ++nf) {
        int col = n0w + nf * 16 + l15;
        float bv = bias[col];
#pragma unroll
        for (int j = 0; j < 4; ++j) {
          int rl = mf * 16 + l4 * 4 + j;
          T[col * 33 + rl] = acc[mf][nf][j] + bv;
        }
      }
    __syncthreads();
    int b = m0 / kNQ, q0 = m0 % kNQ;
    int qv = t & 31, cr = t >> 5;
#pragma unroll
    for (int i = 0; i < 32; ++i) {
      int c = cr + i * 8;
      size_t gi = (size_t)(b * kC + c) * kNQ + q0 + qv;
      Ofp[gi] = T[c * 33 + qv] + resid[gi];
    }
  }
}

// ---------------- K4: off+attn GEMM (N=96) + softmax + coord epilogue --------
// samp layout: [b][h][q][p] float4 {sx, sy, w, 0}
__global__ __launch_bounds__(256) void k_offattn(const ushort* __restrict__ A,
                                                 const ushort* __restrict__ WoffT,
                                                 const ushort* __restrict__ WattnT,
                                                 const float* __restrict__ boff,
                                                 const float* __restrict__ battn,
                                                 const float* __restrict__ refp,
                                                 float4* __restrict__ samp) {
  __shared__ ushort As[32 * 32];
  __shared__ ushort Bs[96 * 32];
  __shared__ float T[32 * 100];
  const int t = threadIdx.x, wave = t >> 6, lane = t & 63;
  const int l15 = lane & 15, l4 = lane >> 4;
  const int m0 = blockIdx.x * 32;
  const int mf = wave & 1, nbase = (wave >> 1) * 48;
  f32x4 acc[3] = {(f32x4)0.f, (f32x4)0.f, (f32x4)0.f};

  for (int kk = 0; kk < 256; kk += 32) {
    if (t < 128) {
      int r = t >> 2, ch = t & 3;
      uint4 d = *(const uint4*)(A + (size_t)(m0 + r) * 256 + kk + ch * 8);
      *(uint4*)((char*)As + r * 64 + ((ch * 16) ^ ((r & 3) << 4))) = d;
    }
#pragma unroll
    for (int i = 0; i < 2; ++i) {
      int id = t + i * 256;
      if (id < 384) {
        int r = id >> 2, ch = id & 3;
        const ushort* src = (r < 64) ? (WoffT + (size_t)r * 256) : (WattnT + (size_t)(r - 64) * 256);
        uint4 d = *(const uint4*)(src + kk + ch * 8);
        *(uint4*)((char*)Bs + r * 64 + ((ch * 16) ^ ((r & 3) << 4))) = d;
      }
    }
    __syncthreads();
    short8 a;
    {
      int r = mf * 16 + l15;
      a = *(const short8*)((char*)As + r * 64 + ((l4 * 16) ^ ((r & 3) << 4)));
    }
#pragma unroll
    for (int nf = 0; nf < 3; ++nf) {
      int r = nbase + nf * 16 + l15;
      short8 bb = *(const short8*)((char*)Bs + r * 64 + ((l4 * 16) ^ ((r & 3) << 4)));
      mfma_bf16(acc[nf], a, bb);
    }
    __syncthreads();
  }
#pragma unroll
  for (int nf = 0; nf < 3; ++nf) {
    int col = nbase + nf * 16 + l15;
    float bv = (col < 64) ? boff[col] : battn[col - 64];
#pragma unroll
    for (int j = 0; j < 4; ++j) {
      int rl = mf * 16 + l4 * 4 + j;
      T[rl * 100 + col] = acc[nf][j] + bv;
    }
  }
  __syncthreads();
  int ql = t >> 3, h = t & 7;
  int b = m0 / kNQ, q = m0 % kNQ + ql;
  float refx = refp[(size_t)(b * kNQ + q) * 2 + 0] * kW - 0.5f;
  float refy = refp[(size_t)(b * kNQ + q) * 2 + 1] * kH - 0.5f;
  float sx[4], sy[4], lg[4];
#pragma unroll
  for (int p = 0; p < 4; ++p) {
    sx[p] = refx + T[ql * 100 + h * 8 + p * 2 + 0];
    sy[p] = refy + T[ql * 100 + h * 8 + p * 2 + 1];
    lg[p] = T[ql * 100 + 64 + h * 4 + p];
  }
  float mx = fmaxf(fmaxf(lg[0], lg[1]), fmaxf(lg[2], lg[3]));
  float e[4], s = 0.f;
#pragma unroll
  for (int p = 0; p < 4; ++p) { e[p] = __expf(lg[p] - mx); s += e[p]; }
  float inv = 1.f / s;
  float4* dst = samp + ((size_t)(b * 8 + h) * kNQ + q) * 4;
#pragma unroll
  for (int p = 0; p < 4; ++p) dst[p] = make_float4(sx[p], sy[p], e[p] * inv, 0.f);
}

// ---------------- K5: deformable sampling + attention aggregate --------------
// v [b][h][q][32] bf16 (plane = 256 KB), samp [b][h][q][p].
// Block = (plane, chunk of 250 q); 96 planes x 16 chunks = 1536 blocks.
// Bijective XCD swizzle: all 16 chunks of a plane (and 12 planes, ~3 MB)
// stay on one XCD -> plane is L2-resident.
__global__ __launch_bounds__(256) void k_sample(const ushort* __restrict__ v,
                                                const float4* __restrict__ samp,
                                                ushort* __restrict__ agg) {
  int orig = blockIdx.x;                       // 1536 = 8 * 192
  int n = (orig & 7) * 192 + (orig >> 3);      // bijective (nwg % 8 == 0)
  int plane = n >> 4;                          // 0..95  == b*8+h
  int chunk = n & 15;                          // 0..15
  int t = threadIdx.x;
  if (t >= 250) return;
  int q = chunk * 250 + t;
  int b = plane >> 3, h = plane & 7;
  const ushort* pv = v + (size_t)plane * kNQ * 32;
  const float4* sp = samp + ((size_t)plane * kNQ + q) * 4;
  float acc[32];
#pragma unroll
  for (int i = 0; i < 32; ++i) acc[i] = 0.f;
#pragma unroll
  for (int p = 0; p < 4; ++p) {
    float4 s = sp[p];
    float x0f = floorf(s.x), y0f = floorf(s.y);
    int x0 = (int)x0f, y0 = (int)y0f;
    float wx = s.x - x0f, wy = s.y - y0f;
#pragma unroll
    for (int ty = 0; ty < 2; ++ty) {
      int iy = y0 + ty;
      if (iy < 0 || iy >= kH) continue;
      float wyv = ty ? wy : 1.f - wy;
#pragma unroll
      for (int tx = 0; tx < 2; ++tx) {
        int ix = x0 + tx;
        if (ix < 0 || ix >= kW) continue;
        float wv = s.z * wyv * (tx ? wx : 1.f - wx);
        const uint4* src = (const uint4*)(pv + (size_t)(iy * kW + ix) * 32);
#pragma unroll
        for (int i = 0; i < 4; ++i) acc8(acc + i * 8, src[i], wv);
      }
    }
  }
  uint o[16];
#pragma unroll
  for (int i = 0; i < 16; ++i) o[i] = pack2(acc[2 * i], acc[2 * i + 1]);
  uint4* dst = (uint4*)(agg + ((size_t)b * kNQ + q) * kC + h * 32);
#pragma unroll
  for (int i = 0; i < 4; ++i) dst[i] = ((uint4*)o)[i];
}

extern "C" void kernel_launch(void* const* d_in, const int* in_sizes, int n_in,
                              void* d_out, int out_size, void* d_ws, size_t ws_size,
                              hipStream_t stream) {
  const float* img   = (const float*)d_in[0];
  const float* grid  = (const float*)d_in[1];
  const float* refp  = (const float*)d_in[2];
  const float* Wv    = (const float*)d_in[3];
  const float* bv    = (const float*)d_in[4];
  const float* Woff  = (const float*)d_in[5];
  const float* boff  = (const float*)d_in[6];
  const float* Wattn = (const float*)d_in[7];
  const float* battn = (const float*)d_in[8];
  const float* Wout  = (const float*)d_in[9];
  const float* bout  = (const float*)d_in[10];
  float* out = (float*)d_out;

  char* ws = (char*)d_ws;
  const size_t SZ = (size_t)kM * kC * 2;  // 24.576 MB per bf16 [M][C] buffer
  ushort* feat   = (ushort*)(ws);
  ushort* warped = (ushort*)(ws + SZ);
  ushort* vbuf   = (ushort*)(ws + 2 * SZ);           // [b][h][q][32] head-major
  float4* samp   = (float4*)(ws + 3 * SZ);           // [b][h][q][4], 24.576 MB
  ushort* WvT    = (ushort*)(ws + 4 * SZ);
  ushort* WoffT  = (ushort*)(ws + 4 * SZ + 131072);
  ushort* WattnT = (ushort*)(ws + 4 * SZ + 131072 + 32768);
  ushort* WoutT  = (ushort*)(ws + 4 * SZ + 131072 + 32768 + 16384);
  ushort* aggb   = warped;  // warped is dead after K3; reuse for agg

  k_wt<<<(65536 + 255) / 256, 256, 0, stream>>>(Wv, WvT, 256, 256);
  k_wt<<<(16384 + 255) / 256, 256, 0, stream>>>(Woff, WoffT, 256, 64);
  k_wt<<<(8192 + 255) / 256, 256, 0, stream>>>(Wattn, WattnT, 256, 32);
  k_wt<<<(65536 + 255) / 256, 256, 0, stream>>>(Wout, WoutT, 256, 256);

  k_transpose<<<dim3(63, 4, 12), 256, 0, stream>>>(img, feat);
  k_warp<<<1500, 256, 0, stream>>>(feat, grid, warped);
  k_gemm256<0><<<kM / 32, 256, 18432, stream>>>(warped, WvT, bv, vbuf, nullptr, nullptr);
  k_offattn<<<kM / 32, 256, 0, stream>>>(feat, WoffT, WattnT, boff, battn, refp, samp);
  k_sample<<<1536, 256, 0, stream>>>(vbuf, samp, aggb);
  k_gemm256<1><<<kM / 32, 256, 33792, stream>>>(aggb, WoutT, bout, nullptr, out, img);
}

// Round 6
// 141.818 us; speedup vs baseline: 1.4213x; 1.1450x over previous
//
#include <hip/hip_runtime.h>

#define DEVINL __device__ __forceinline__

typedef __attribute__((ext_vector_type(4))) float f32x4;
typedef __attribute__((ext_vector_type(8))) short short8;

constexpr int kBN = 12, kC = 256, kH = 40, kW = 100;
constexpr int kNQ = kH * kW;      // 4000
constexpr int kM = kBN * kNQ;     // 48000

DEVINL float bflo(uint p) { union { uint i; float f; } v; v.i = p << 16; return v.f; }
DEVINL float bfhi(uint p) { union { uint i; float f; } v; v.i = p & 0xffff0000u; return v.f; }
DEVINL ushort f2bf(float f) {
  union { float f; uint i; } v; v.f = f;
  uint i = v.i;
  return (ushort)((i + 0x7fffu + ((i >> 16) & 1u)) >> 16);  // RNE
}
DEVINL uint pack2(float a, float b) { return (uint)f2bf(a) | ((uint)f2bf(b) << 16); }

DEVINL void mfma_bf16(f32x4& acc, short8 a, short8 b) {
  acc = __builtin_amdgcn_mfma_f32_16x16x32_bf16(a, b, acc, 0, 0, 0);
}

DEVINL void acc8(float* acc, uint4 d, float wv) {
  acc[0] += wv * bflo(d.x); acc[1] += wv * bfhi(d.x);
  acc[2] += wv * bflo(d.y); acc[3] += wv * bfhi(d.y);
  acc[4] += wv * bflo(d.z); acc[5] += wv * bfhi(d.z);
  acc[6] += wv * bflo(d.w); acc[7] += wv * bfhi(d.w);
}

// ---------------- K0: weight transpose + bf16 convert: W[K][N] -> WT[N][K] ----
__global__ __launch_bounds__(256) void k_wt(const float* __restrict__ W,
                                            ushort* __restrict__ WT, int K, int N) {
  int idx = blockIdx.x * 256 + threadIdx.x;
  if (idx >= K * N) return;
  int n = idx / K, k = idx - n * K;
  WT[idx] = f2bf(W[k * N + n]);
}

// ---------------- K1: img NCHW f32 -> feat [b][q][c] bf16 --------------------
__global__ __launch_bounds__(256) void k_transpose(const float* __restrict__ img,
                                                   ushort* __restrict__ feat) {
  __shared__ ushort tile[64][66];
  int b = blockIdx.z, c0 = blockIdx.y * 64, q0 = blockIdx.x * 64;
  int t = threadIdx.x;
  int ql = t & 63, cl = t >> 6;
#pragma unroll
  for (int i = 0; i < 16; ++i) {
    int c = cl + i * 4, q = q0 + ql;
    float v = (q < kNQ) ? img[(size_t)(b * kC + c0 + c) * kNQ + q] : 0.f;
    tile[c][ql] = f2bf(v);
  }
  __syncthreads();
  int cc = t & 63, qr = t >> 6;
#pragma unroll
  for (int i = 0; i < 16; ++i) {
    int qlo = qr + i * 4, q = q0 + qlo;
    if (q < kNQ) feat[(size_t)(b * kNQ + q) * kC + c0 + cc] = tile[cc][qlo];
  }
}

// ---------------- K2: BEV warp: bilinear(feat, grid) -> warped bf16 ----------
// 32 lanes per q, 1 uint4 (16B) per lane per corner -> each corner-visit is ONE
// fully-coalesced 512B instruction (TA touches /4 vs 4-inst version).
// Grid 6000 = 8*750 bijective XCD swizzle: each XCD ~1.5 b-slabs (~3MB L2).
__global__ __launch_bounds__(256) void k_warp(const ushort* __restrict__ feat,
                                              const float* __restrict__ grid,
                                              ushort* __restrict__ warped) {
  int orig = blockIdx.x;
  int n = (orig & 7) * 750 + (orig >> 3);     // bijective, 6000 = 8*750
  int t = threadIdx.x;
  int ql = t >> 5, g = t & 31;                // 8 q per block, 32 lanes per q
  int gq = n * 8 + ql;                        // global row in [0, 48000)
  int b = gq / kNQ, q = gq - b * kNQ;
  float gx = grid[(size_t)gq * 2 + 0] * kW - 0.5f;
  float gy = grid[(size_t)gq * 2 + 1] * kH - 0.5f;
  float x0f = floorf(gx), y0f = floorf(gy);
  int x0 = (int)x0f, y0 = (int)y0f;
  float wx = gx - x0f, wy = gy - y0f;
  float acc[8];
#pragma unroll
  for (int i = 0; i < 8; ++i) acc[i] = 0.f;
  const ushort* fb = feat + (size_t)b * kNQ * kC + g * 8;
#pragma unroll
  for (int ty = 0; ty < 2; ++ty) {
    int iy = y0 + ty;
    if (iy < 0 || iy >= kH) continue;
    float wyv = ty ? wy : 1.f - wy;
#pragma unroll
    for (int tx = 0; tx < 2; ++tx) {
      int ix = x0 + tx;
      if (ix < 0 || ix >= kW) continue;
      float wv = wyv * (tx ? wx : 1.f - wx);
      uint4 d = *(const uint4*)(fb + (size_t)(iy * kW + ix) * kC);
      acc8(acc, d, wv);
    }
  }
  uint o[4] = {pack2(acc[0], acc[1]), pack2(acc[2], acc[3]),
               pack2(acc[4], acc[5]), pack2(acc[6], acc[7])};
  *(uint4*)(warped + (size_t)gq * kC + g * 8) = *(uint4*)o;
}

// ---------------- K3/K6: MFMA GEMM, M-tile 32, N=256, K=256 ------------------
// A [M][256] bf16 row-major, BT [256][256] bf16 (pre-transposed weights [N][K]).
// EPI 0: v store, HEAD-MAJOR: vbuf[((b*8+h)*kNQ + q)*32 + ch]   (bf16)
// EPI 1: out NCHW fp32: acc + bias[col] + resid, via LDS transpose
template <int EPI>
__global__ __launch_bounds__(256) void k_gemm256(const ushort* __restrict__ A,
                                                 const ushort* __restrict__ BT,
                                                 const float* __restrict__ bias,
                                                 ushort* __restrict__ Obf,
                                                 float* __restrict__ Ofp,
                                                 const float* __restrict__ resid) {
  extern __shared__ char smem[];
  ushort* As = (ushort*)smem;           // [32][32] bf16, 64B rows, XOR-swizzled
  ushort* Bs = (ushort*)(smem + 2048);  // [256][32]
  const int t = threadIdx.x, wave = t >> 6, lane = t & 63;
  const int l15 = lane & 15, l4 = lane >> 4;
  const int m0 = blockIdx.x * 32;
  const int n0w = wave * 64;
  f32x4 acc[2][4];
#pragma unroll
  for (int i = 0; i < 2; ++i)
#pragma unroll
    for (int j = 0; j < 4; ++j) acc[i][j] = (f32x4)0.f;

  for (int kk = 0; kk < 256; kk += 32) {
    if (t < 128) {
      int r = t >> 2, ch = t & 3;
      uint4 d = *(const uint4*)(A + (size_t)(m0 + r) * 256 + kk + ch * 8);
      *(uint4*)((char*)As + r * 64 + ((ch * 16) ^ ((r & 3) << 4))) = d;
    }
#pragma unroll
    for (int i = 0; i < 4; ++i) {
      int idx = t + i * 256;
      int r = idx >> 2, ch = idx & 3;
      uint4 d = *(const uint4*)(BT + (size_t)r * 256 + kk + ch * 8);
      *(uint4*)((char*)Bs + r * 64 + ((ch * 16) ^ ((r & 3) << 4))) = d;
    }
    __syncthreads();
    short8 a[2], bfr[4];
#pragma unroll
    for (int mf = 0; mf < 2; ++mf) {
      int r = mf * 16 + l15;
      a[mf] = *(const short8*)((char*)As + r * 64 + ((l4 * 16) ^ ((r & 3) << 4)));
    }
#pragma unroll
    for (int nf = 0; nf < 4; ++nf) {
      int r = n0w + nf * 16 + l15;
      bfr[nf] = *(const short8*)((char*)Bs + r * 64 + ((l4 * 16) ^ ((r & 3) << 4)));
    }
#pragma unroll
    for (int mf = 0; mf < 2; ++mf)
#pragma unroll
      for (int nf = 0; nf < 4; ++nf) mfma_bf16(acc[mf][nf], a[mf], bfr[nf]);
    __syncthreads();
  }

  if (EPI == 0) {
    int b = m0 / kNQ, q0 = m0 % kNQ;
#pragma unroll
    for (int mf = 0; mf < 2; ++mf)
#pragma unroll
      for (int nf = 0; nf < 4; ++nf) {
        int col = n0w + nf * 16 + l15;
        float bv = bias[col];
        int h = col >> 5, ch = col & 31;
#pragma unroll
        for (int j = 0; j < 4; ++j) {
          int q = q0 + mf * 16 + l4 * 4 + j;
          Obf[((size_t)(b * 8 + h) * kNQ + q) * 32 + ch] = f2bf(acc[mf][nf][j] + bv);
        }
      }
  } else {
    float* T = (float*)smem;  // [256][33] fp32 (aliases As/Bs, dead after loop)
#pragma unroll
    for (int mf = 0; mf < 2; ++mf)
#pragma unroll
      for (int nf = 0; nf < 4; ++nf) {
        int col = n0w + nf * 16 + l15;
        float bv = bias[col];
#pragma unroll
        for (int j = 0; j < 4; ++j) {
          int rl = mf * 16 + l4 * 4 + j;
          T[col * 33 + rl] = acc[mf][nf][j] + bv;
        }
      }
    __syncthreads();
    int b = m0 / kNQ, q0 = m0 % kNQ;
    int qv = t & 31, cr = t >> 5;
#pragma unroll
    for (int i = 0; i < 32; ++i) {
      int c = cr + i * 8;
      size_t gi = (size_t)(b * kC + c) * kNQ + q0 + qv;
      Ofp[gi] = T[c * 33 + qv] + resid[gi];
    }
  }
}

// ---------------- K4: off+attn GEMM (N=96) + softmax + coord epilogue --------
// samp layout: [b][h][q][p] float4 {sx, sy, w, 0}
__global__ __launch_bounds__(256) void k_offattn(const ushort* __restrict__ A,
                                                 const ushort* __restrict__ WoffT,
                                                 const ushort* __restrict__ WattnT,
                                                 const float* __restrict__ boff,
                                                 const float* __restrict__ battn,
                                                 const float* __restrict__ refp,
                                                 float4* __restrict__ samp) {
  __shared__ ushort As[32 * 32];
  __shared__ ushort Bs[96 * 32];
  __shared__ float T[32 * 100];
  const int t = threadIdx.x, wave = t >> 6, lane = t & 63;
  const int l15 = lane & 15, l4 = lane >> 4;
  const int m0 = blockIdx.x * 32;
  const int mf = wave & 1, nbase = (wave >> 1) * 48;
  f32x4 acc[3] = {(f32x4)0.f, (f32x4)0.f, (f32x4)0.f};

  for (int kk = 0; kk < 256; kk += 32) {
    if (t < 128) {
      int r = t >> 2, ch = t & 3;
      uint4 d = *(const uint4*)(A + (size_t)(m0 + r) * 256 + kk + ch * 8);
      *(uint4*)((char*)As + r * 64 + ((ch * 16) ^ ((r & 3) << 4))) = d;
    }
#pragma unroll
    for (int i = 0; i < 2; ++i) {
      int id = t + i * 256;
      if (id < 384) {
        int r = id >> 2, ch = id & 3;
        const ushort* src = (r < 64) ? (WoffT + (size_t)r * 256) : (WattnT + (size_t)(r - 64) * 256);
        uint4 d = *(const uint4*)(src + kk + ch * 8);
        *(uint4*)((char*)Bs + r * 64 + ((ch * 16) ^ ((r & 3) << 4))) = d;
      }
    }
    __syncthreads();
    short8 a;
    {
      int r = mf * 16 + l15;
      a = *(const short8*)((char*)As + r * 64 + ((l4 * 16) ^ ((r & 3) << 4)));
    }
#pragma unroll
    for (int nf = 0; nf < 3; ++nf) {
      int r = nbase + nf * 16 + l15;
      short8 bb = *(const short8*)((char*)Bs + r * 64 + ((l4 * 16) ^ ((r & 3) << 4)));
      mfma_bf16(acc[nf], a, bb);
    }
    __syncthreads();
  }
#pragma unroll
  for (int nf = 0; nf < 3; ++nf) {
    int col = nbase + nf * 16 + l15;
    float bv = (col < 64) ? boff[col] : battn[col - 64];
#pragma unroll
    for (int j = 0; j < 4; ++j) {
      int rl = mf * 16 + l4 * 4 + j;
      T[rl * 100 + col] = acc[nf][j] + bv;
    }
  }
  __syncthreads();
  int ql = t >> 3, h = t & 7;
  int b = m0 / kNQ, q = m0 % kNQ + ql;
  float refx = refp[(size_t)(b * kNQ + q) * 2 + 0] * kW - 0.5f;
  float refy = refp[(size_t)(b * kNQ + q) * 2 + 1] * kH - 0.5f;
  float sx[4], sy[4], lg[4];
#pragma unroll
  for (int p = 0; p < 4; ++p) {
    sx[p] = refx + T[ql * 100 + h * 8 + p * 2 + 0];
    sy[p] = refy + T[ql * 100 + h * 8 + p * 2 + 1];
    lg[p] = T[ql * 100 + 64 + h * 4 + p];
  }
  float mx = fmaxf(fmaxf(lg[0], lg[1]), fmaxf(lg[2], lg[3]));
  float e[4], s = 0.f;
#pragma unroll
  for (int p = 0; p < 4; ++p) { e[p] = __expf(lg[p] - mx); s += e[p]; }
  float inv = 1.f / s;
  float4* dst = samp + ((size_t)(b * 8 + h) * kNQ + q) * 4;
#pragma unroll
  for (int p = 0; p < 4; ++p) dst[p] = make_float4(sx[p], sy[p], e[p] * inv, 0.f);
}

// ---------------- K5: deformable sampling + attention aggregate --------------
// v [b][h][q][32] bf16 (plane = 256 KB), samp [b][h][q][p].
// 4 lanes per q (lane g owns channels g*8..g*8+7): each corner-visit is ONE
// coalesced instruction (4 lanes x 16B = the pixel's 64B). samp read: lane g
// loads point g's float4, broadcast within the 4-lane group via __shfl.
// Grid 6048 = 8*756, plane-major bijective XCD swizzle (12 planes = 3MB/XCD).
__global__ __launch_bounds__(256) void k_sample(const ushort* __restrict__ v,
                                                const float4* __restrict__ samp,
                                                ushort* __restrict__ agg) {
  int orig = blockIdx.x;
  int n = (orig & 7) * 756 + (orig >> 3);      // bijective, 6048 = 8*756
  int plane = n / 63, chunk = n - plane * 63;  // 96 planes x 63 chunks
  int t = threadIdx.x;
  int ql = t >> 2, g = t & 3;                  // 64 q per block, 4 lanes per q
  int q = chunk * 64 + ql;
  if (q >= kNQ) return;
  int b = plane >> 3, h = plane & 7;
  const ushort* pv = v + (size_t)plane * kNQ * 32 + g * 8;
  const int lane = t & 63, gbase = lane & ~3;

  float4 mys = samp[((size_t)plane * kNQ + q) * 4 + g];  // lane g owns point g
  float acc[8];
#pragma unroll
  for (int i = 0; i < 8; ++i) acc[i] = 0.f;
#pragma unroll
  for (int p = 0; p < 4; ++p) {
    float sxp = __shfl(mys.x, gbase + p);
    float syp = __shfl(mys.y, gbase + p);
    float wp  = __shfl(mys.z, gbase + p);
    float x0f = floorf(sxp), y0f = floorf(syp);
    int x0 = (int)x0f, y0 = (int)y0f;
    float wx = sxp - x0f, wy = syp - y0f;
#pragma unroll
    for (int ty = 0; ty < 2; ++ty) {
      int iy = y0 + ty;
      if (iy < 0 || iy >= kH) continue;
      float wyv = ty ? wy : 1.f - wy;
#pragma unroll
      for (int tx = 0; tx < 2; ++tx) {
        int ix = x0 + tx;
        if (ix < 0 || ix >= kW) continue;
        float wv = wp * wyv * (tx ? wx : 1.f - wx);
        uint4 d = *(const uint4*)(pv + (size_t)(iy * kW + ix) * 32);
        acc8(acc, d, wv);
      }
    }
  }
  uint o[4] = {pack2(acc[0], acc[1]), pack2(acc[2], acc[3]),
               pack2(acc[4], acc[5]), pack2(acc[6], acc[7])};
  *(uint4*)(agg + ((size_t)b * kNQ + q) * kC + h * 32 + g * 8) = *(uint4*)o;
}

extern "C" void kernel_launch(void* const* d_in, const int* in_sizes, int n_in,
                              void* d_out, int out_size, void* d_ws, size_t ws_size,
                              hipStream_t stream) {
  const float* img   = (const float*)d_in[0];
  const float* grid  = (const float*)d_in[1];
  const float* refp  = (const float*)d_in[2];
  const float* Wv    = (const float*)d_in[3];
  const float* bv    = (const float*)d_in[4];
  const float* Woff  = (const float*)d_in[5];
  const float* boff  = (const float*)d_in[6];
  const float* Wattn = (const float*)d_in[7];
  const float* battn = (const float*)d_in[8];
  const float* Wout  = (const float*)d_in[9];
  const float* bout  = (const float*)d_in[10];
  float* out = (float*)d_out;

  char* ws = (char*)d_ws;
  const size_t SZ = (size_t)kM * kC * 2;  // 24.576 MB per bf16 [M][C] buffer
  ushort* feat   = (ushort*)(ws);
  ushort* warped = (ushort*)(ws + SZ);
  ushort* vbuf   = (ushort*)(ws + 2 * SZ);           // [b][h][q][32] head-major
  float4* samp   = (float4*)(ws + 3 * SZ);           // [b][h][q][4], 24.576 MB
  ushort* WvT    = (ushort*)(ws + 4 * SZ);
  ushort* WoffT  = (ushort*)(ws + 4 * SZ + 131072);
  ushort* WattnT = (ushort*)(ws + 4 * SZ + 131072 + 32768);
  ushort* WoutT  = (ushort*)(ws + 4 * SZ + 131072 + 32768 + 16384);
  ushort* aggb   = warped;  // warped is dead after K3; reuse for agg

  k_wt<<<(65536 + 255) / 256, 256, 0, stream>>>(Wv, WvT, 256, 256);
  k_wt<<<(16384 + 255) / 256, 256, 0, stream>>>(Woff, WoffT, 256, 64);
  k_wt<<<(8192 + 255) / 256, 256, 0, stream>>>(Wattn, WattnT, 256, 32);
  k_wt<<<(65536 + 255) / 256, 256, 0, stream>>>(Wout, WoutT, 256, 256);

  k_transpose<<<dim3(63, 4, 12), 256, 0, stream>>>(img, feat);
  k_warp<<<6000, 256, 0, stream>>>(feat, grid, warped);
  k_gemm256<0><<<kM / 32, 256, 18432, stream>>>(warped, WvT, bv, vbuf, nullptr, nullptr);
  k_offattn<<<kM / 32, 256, 0, stream>>>(feat, WoffT, WattnT, boff, battn, refp, samp);
  k_sample<<<6048, 256, 0, stream>>>(vbuf, samp, aggb);
  k_gemm256<1><<<kM / 32, 256, 33792, stream>>>(aggb, WoutT, bout, nullptr, out, img);
}

// Round 7
// 135.063 us; speedup vs baseline: 1.4924x; 1.0500x over previous
//
#include <hip/hip_runtime.h>

#define DEVINL __device__ __forceinline__

typedef __attribute__((ext_vector_type(4))) float f32x4;
typedef __attribute__((ext_vector_type(8))) short short8;

constexpr int kBN = 12, kC = 256, kH = 40, kW = 100;
constexpr int kNQ = kH * kW;      // 4000
constexpr int kM = kBN * kNQ;     // 48000

DEVINL float bflo(uint p) { union { uint i; float f; } v; v.i = p << 16; return v.f; }
DEVINL float bfhi(uint p) { union { uint i; float f; } v; v.i = p & 0xffff0000u; return v.f; }
DEVINL ushort f2bf(float f) {
  union { float f; uint i; } v; v.f = f;
  uint i = v.i;
  return (ushort)((i + 0x7fffu + ((i >> 16) & 1u)) >> 16);  // RNE
}
DEVINL uint pack2(float a, float b) { return (uint)f2bf(a) | ((uint)f2bf(b) << 16); }

DEVINL void mfma_bf16(f32x4& acc, short8 a, short8 b) {
  acc = __builtin_amdgcn_mfma_f32_16x16x32_bf16(a, b, acc, 0, 0, 0);
}

DEVINL void gload16(const ushort* g, char* lds) {
  __builtin_amdgcn_global_load_lds(
      (const __attribute__((address_space(1))) uint*)g,
      (__attribute__((address_space(3))) uint*)lds, 16, 0, 0);
}

DEVINL void acc8(float* acc, uint4 d, float wv) {
  acc[0] += wv * bflo(d.x); acc[1] += wv * bfhi(d.x);
  acc[2] += wv * bflo(d.y); acc[3] += wv * bfhi(d.y);
  acc[4] += wv * bflo(d.z); acc[5] += wv * bfhi(d.z);
  acc[6] += wv * bflo(d.w); acc[7] += wv * bfhi(d.w);
}

// ---------------- K0: weight transpose + bf16 convert: W[K][N] -> WT[N][K] ----
__global__ __launch_bounds__(256) void k_wt(const float* __restrict__ W,
                                            ushort* __restrict__ WT, int K, int N) {
  int idx = blockIdx.x * 256 + threadIdx.x;
  if (idx >= K * N) return;
  int n = idx / K, k = idx - n * K;
  WT[idx] = f2bf(W[k * N + n]);
}

// ---------------- K1: img NCHW f32 -> feat [b][q][c] bf16 --------------------
__global__ __launch_bounds__(256) void k_transpose(const float* __restrict__ img,
                                                   ushort* __restrict__ feat) {
  __shared__ ushort tile[64][66];
  int b = blockIdx.z, c0 = blockIdx.y * 64, q0 = blockIdx.x * 64;
  int t = threadIdx.x;
  int ql = t & 63, cl = t >> 6;
#pragma unroll
  for (int i = 0; i < 16; ++i) {
    int c = cl + i * 4, q = q0 + ql;
    float v = (q < kNQ) ? img[(size_t)(b * kC + c0 + c) * kNQ + q] : 0.f;
    tile[c][ql] = f2bf(v);
  }
  __syncthreads();
  int cc = t & 63, qr = t >> 6;
#pragma unroll
  for (int i = 0; i < 16; ++i) {
    int qlo = qr + i * 4, q = q0 + qlo;
    if (q < kNQ) feat[(size_t)(b * kNQ + q) * kC + c0 + cc] = tile[cc][qlo];
  }
}

// ---------------- K2: BEV warp: bilinear(feat, grid) -> warped bf16 ----------
__global__ __launch_bounds__(256) void k_warp(const ushort* __restrict__ feat,
                                              const float* __restrict__ grid,
                                              ushort* __restrict__ warped) {
  int orig = blockIdx.x;
  int n = (orig & 7) * 750 + (orig >> 3);     // bijective, 6000 = 8*750
  int t = threadIdx.x;
  int ql = t >> 5, g = t & 31;                // 8 q per block, 32 lanes per q
  int gq = n * 8 + ql;
  int b = gq / kNQ;
  float gx = grid[(size_t)gq * 2 + 0] * kW - 0.5f;
  float gy = grid[(size_t)gq * 2 + 1] * kH - 0.5f;
  float x0f = floorf(gx), y0f = floorf(gy);
  int x0 = (int)x0f, y0 = (int)y0f;
  float wx = gx - x0f, wy = gy - y0f;
  float acc[8];
#pragma unroll
  for (int i = 0; i < 8; ++i) acc[i] = 0.f;
  const ushort* fb = feat + (size_t)b * kNQ * kC + g * 8;
#pragma unroll
  for (int ty = 0; ty < 2; ++ty) {
    int iy = y0 + ty;
    if (iy < 0 || iy >= kH) continue;
    float wyv = ty ? wy : 1.f - wy;
#pragma unroll
    for (int tx = 0; tx < 2; ++tx) {
      int ix = x0 + tx;
      if (ix < 0 || ix >= kW) continue;
      float wv = wyv * (tx ? wx : 1.f - wx);
      uint4 d = *(const uint4*)(fb + (size_t)(iy * kW + ix) * kC);
      acc8(acc, d, wv);
    }
  }
  uint o[4] = {pack2(acc[0], acc[1]), pack2(acc[2], acc[3]),
               pack2(acc[4], acc[5]), pack2(acc[6], acc[7])};
  *(uint4*)(warped + (size_t)gq * kC + g * 8) = *(uint4*)o;
}

// ---------------- K3/K6: MFMA GEMM v2: BM=64, BN=256, BK=32 ------------------
// 256 thr = 4 waves (1M x 4N), each wave 64x64 (4x4 frags).
// global_load_lds direct staging; rule-21 both-sides XOR swizzle:
//   source chunk c^( (r>>1)&3 ), ds_read slot l4^( (r>>1)&3 ).
// Grid 756 = 12 b-slabs x 63 (BM=64; last block 32 rows).
// EPI 0: v head-major bf16; EPI 1: NCHW fp32 + resid via per-wave LDS transpose.
template <int EPI>
__global__ __launch_bounds__(256) void k_gemm256(const ushort* __restrict__ A,
                                                 const ushort* __restrict__ BT,
                                                 const float* __restrict__ bias,
                                                 ushort* __restrict__ Obf,
                                                 float* __restrict__ Ofp,
                                                 const float* __restrict__ resid) {
  extern __shared__ char smem[];
  char* As = smem;            // [64][32] bf16 = 4096 B (src-swizzled)
  char* Bs = smem + 4096;     // [256][32] bf16 = 16384 B
  const int t = threadIdx.x, wave = t >> 6, lane = t & 63;
  const int l15 = lane & 15, l4 = lane >> 4;
  const int b = blockIdx.x / 63, mb = blockIdx.x % 63;
  const int q0 = mb * 64;
  const int nrows = (kNQ - q0 < 64) ? (kNQ - q0) : 64;
  const int n0w = wave * 64;
  const int ra = t >> 2, ca = t & 3;
  const int sca = ca ^ ((ra >> 1) & 3);
  const ushort* gA = A + ((size_t)b * kNQ + q0 + ra) * 256 + sca * 8;
  const ushort* gB = BT + (size_t)ra * 256 + sca * 8;
  const bool doA = (ra < nrows);

  f32x4 acc[4][4];
#pragma unroll
  for (int i = 0; i < 4; ++i)
#pragma unroll
    for (int j = 0; j < 4; ++j) acc[i][j] = (f32x4)0.f;

  for (int kk = 0; kk < 256; kk += 32) {
    if (doA) gload16(gA + kk, As + t * 16);
#pragma unroll
    for (int i = 0; i < 4; ++i)
      gload16(gB + (size_t)i * 64 * 256 + kk, Bs + (i * 256 + t) * 16);
    __syncthreads();
    short8 af[4], bf[4];
#pragma unroll
    for (int mf = 0; mf < 4; ++mf) {
      int r = mf * 16 + l15;
      int sl = l4 ^ ((r >> 1) & 3);
      af[mf] = *(const short8*)(As + r * 64 + sl * 16);
    }
#pragma unroll
    for (int nf = 0; nf < 4; ++nf) {
      int r = n0w + nf * 16 + l15;
      int sl = l4 ^ ((r >> 1) & 3);
      bf[nf] = *(const short8*)(Bs + r * 64 + sl * 16);
    }
#pragma unroll
    for (int mf = 0; mf < 4; ++mf)
#pragma unroll
      for (int nf = 0; nf < 4; ++nf) mfma_bf16(acc[mf][nf], af[mf], bf[nf]);
    __syncthreads();
  }

  if (EPI == 0) {
#pragma unroll
    for (int mf = 0; mf < 4; ++mf) {
      if (mf * 16 >= nrows) continue;
      int q = q0 + mf * 16 + l4 * 4;
#pragma unroll
      for (int nf = 0; nf < 4; ++nf) {
        int col = n0w + nf * 16 + l15;
        float bv = bias[col];
        int h = col >> 5, ch = col & 31;
        ushort* dst = Obf + (size_t)(b * 8 + h) * kNQ * 32 + ch;
#pragma unroll
        for (int j = 0; j < 4; ++j)
          dst[(size_t)(q + j) * 32] = f2bf(acc[mf][nf][j] + bv);
      }
    }
  } else {
    // per-wave transpose scratch: [16 cols][68 rows] fp32 = 4352 B per wave
    float* Tw = (float*)(smem + wave * 4352);
#pragma unroll
    for (int nf = 0; nf < 4; ++nf) {
      float bv = bias[n0w + nf * 16 + l15];
#pragma unroll
      for (int mf = 0; mf < 4; ++mf)
#pragma unroll
        for (int j = 0; j < 4; ++j)
          Tw[l15 * 68 + mf * 16 + l4 * 4 + j] = acc[mf][nf][j] + bv;
      int c = l15, hi = l4;                 // lane -> (col, row-seg of 16)
      int rs = hi * 16;
      if (rs < nrows) {
        int col = n0w + nf * 16 + c;
        size_t gi = ((size_t)b * kC + col) * kNQ + q0 + rs;
#pragma unroll
        for (int k = 0; k < 4; ++k) {
          float4 tv = *(float4*)(&Tw[c * 68 + rs + k * 4]);
          float4 rv = *(const float4*)(resid + gi + k * 4);
          tv.x += rv.x; tv.y += rv.y; tv.z += rv.z; tv.w += rv.w;
          *(float4*)(Ofp + gi + k * 4) = tv;
        }
      }
    }
  }
}

// ---------------- K4: off+attn GEMM v2 (BM=64, BN=96) + softmax --------------
// 4 waves, grid 2M x 2N: wave = 32 rows x 48 cols (2x3 frags).
// samp layout: [b][h][q][p] float4 {sx, sy, w, 0}
__global__ __launch_bounds__(256) void k_offattn(const ushort* __restrict__ A,
                                                 const ushort* __restrict__ WoffT,
                                                 const ushort* __restrict__ WattnT,
                                                 const float* __restrict__ boff,
                                                 const float* __restrict__ battn,
                                                 const float* __restrict__ refp,
                                                 float4* __restrict__ samp) {
  extern __shared__ char smem[];
  char* As = smem;            // [64][32] = 4096 B
  char* Bs = smem + 4096;     // [96][32] = 6144 B
  float* T = (float*)smem;    // epilogue: [64][101] fp32 = 25856 B (aliases)
  const int t = threadIdx.x, wave = t >> 6, lane = t & 63;
  const int l15 = lane & 15, l4 = lane >> 4;
  const int b = blockIdx.x / 63, mb = blockIdx.x % 63;
  const int q0 = mb * 64;
  const int nrows = (kNQ - q0 < 64) ? (kNQ - q0) : 64;
  const int wr = wave >> 1, wc = wave & 1;
  const int ra = t >> 2, ca = t & 3;
  const int sca = ca ^ ((ra >> 1) & 3);
  const ushort* gA = A + ((size_t)b * kNQ + q0 + ra) * 256 + sca * 8;
  const ushort* gB0 = WoffT + (size_t)ra * 256 + sca * 8;
  const ushort* gB1 = WattnT + (size_t)ra * 256 + sca * 8;  // used by t<128 (ra<32)
  const bool doA = (ra < nrows);

  f32x4 acc[2][3];
#pragma unroll
  for (int i = 0; i < 2; ++i)
#pragma unroll
    for (int j = 0; j < 3; ++j) acc[i][j] = (f32x4)0.f;

  for (int kk = 0; kk < 256; kk += 32) {
    if (doA) gload16(gA + kk, As + t * 16);
    gload16(gB0 + kk, Bs + t * 16);
    if (t < 128) gload16(gB1 + kk, Bs + (256 + t) * 16);
    __syncthreads();
    short8 af[2], bf[3];
#pragma unroll
    for (int mf = 0; mf < 2; ++mf) {
      int r = wr * 32 + mf * 16 + l15;
      int sl = l4 ^ ((r >> 1) & 3);
      af[mf] = *(const short8*)(As + r * 64 + sl * 16);
    }
#pragma unroll
    for (int nf = 0; nf < 3; ++nf) {
      int r = wc * 48 + nf * 16 + l15;
      int sl = l4 ^ ((r >> 1) & 3);
      bf[nf] = *(const short8*)(Bs + r * 64 + sl * 16);
    }
#pragma unroll
    for (int mf = 0; mf < 2; ++mf)
#pragma unroll
      for (int nf = 0; nf < 3; ++nf) mfma_bf16(acc[mf][nf], af[mf], bf[nf]);
    __syncthreads();
  }

#pragma unroll
  for (int nf = 0; nf < 3; ++nf) {
    int col = wc * 48 + nf * 16 + l15;
    float bv = (col < 64) ? boff[col] : battn[col - 64];
#pragma unroll
    for (int mf = 0; mf < 2; ++mf)
#pragma unroll
      for (int j = 0; j < 4; ++j) {
        int row = wr * 32 + mf * 16 + l4 * 4 + j;
        T[row * 101 + col] = acc[mf][nf][j] + bv;
      }
  }
  __syncthreads();
  int row = t >> 2;
  if (row < nrows) {
    int q = q0 + row;
    float refx = refp[((size_t)b * kNQ + q) * 2 + 0] * kW - 0.5f;
    float refy = refp[((size_t)b * kNQ + q) * 2 + 1] * kH - 0.5f;
#pragma unroll
    for (int hi2 = 0; hi2 < 2; ++hi2) {
      int h = (t & 3) + hi2 * 4;
      float sx[4], sy[4], lg[4];
#pragma unroll
      for (int p = 0; p < 4; ++p) {
        sx[p] = refx + T[row * 101 + h * 8 + p * 2 + 0];
        sy[p] = refy + T[row * 101 + h * 8 + p * 2 + 1];
        lg[p] = T[row * 101 + 64 + h * 4 + p];
      }
      float mx = fmaxf(fmaxf(lg[0], lg[1]), fmaxf(lg[2], lg[3]));
      float e[4], s = 0.f;
#pragma unroll
      for (int p = 0; p < 4; ++p) { e[p] = __expf(lg[p] - mx); s += e[p]; }
      float inv = 1.f / s;
      float4* dst = samp + ((size_t)(b * 8 + h) * kNQ + q) * 4;
#pragma unroll
      for (int p = 0; p < 4; ++p) dst[p] = make_float4(sx[p], sy[p], e[p] * inv, 0.f);
    }
  }
}

// ---------------- K5: deformable sampling + attention aggregate --------------
__global__ __launch_bounds__(256) void k_sample(const ushort* __restrict__ v,
                                                const float4* __restrict__ samp,
                                                ushort* __restrict__ agg) {
  int orig = blockIdx.x;
  int n = (orig & 7) * 756 + (orig >> 3);      // bijective, 6048 = 8*756
  int plane = n / 63, chunk = n - plane * 63;  // 96 planes x 63 chunks
  int t = threadIdx.x;
  int ql = t >> 2, g = t & 3;                  // 64 q per block, 4 lanes per q
  int q = chunk * 64 + ql;
  if (q >= kNQ) return;
  int b = plane >> 3, h = plane & 7;
  const ushort* pv = v + (size_t)plane * kNQ * 32 + g * 8;
  const int lane = t & 63, gbase = lane & ~3;

  float4 mys = samp[((size_t)plane * kNQ + q) * 4 + g];  // lane g owns point g
  float acc[8];
#pragma unroll
  for (int i = 0; i < 8; ++i) acc[i] = 0.f;
#pragma unroll
  for (int p = 0; p < 4; ++p) {
    float sxp = __shfl(mys.x, gbase + p);
    float syp = __shfl(mys.y, gbase + p);
    float wp  = __shfl(mys.z, gbase + p);
    float x0f = floorf(sxp), y0f = floorf(syp);
    int x0 = (int)x0f, y0 = (int)y0f;
    float wx = sxp - x0f, wy = syp - y0f;
#pragma unroll
    for (int ty = 0; ty < 2; ++ty) {
      int iy = y0 + ty;
      if (iy < 0 || iy >= kH) continue;
      float wyv = ty ? wy : 1.f - wy;
#pragma unroll
      for (int tx = 0; tx < 2; ++tx) {
        int ix = x0 + tx;
        if (ix < 0 || ix >= kW) continue;
        float wv = wp * wyv * (tx ? wx : 1.f - wx);
        uint4 d = *(const uint4*)(pv + (size_t)(iy * kW + ix) * 32);
        acc8(acc, d, wv);
      }
    }
  }
  uint o[4] = {pack2(acc[0], acc[1]), pack2(acc[2], acc[3]),
               pack2(acc[4], acc[5]), pack2(acc[6], acc[7])};
  *(uint4*)(agg + ((size_t)b * kNQ + q) * kC + h * 32 + g * 8) = *(uint4*)o;
}

extern "C" void kernel_launch(void* const* d_in, const int* in_sizes, int n_in,
                              void* d_out, int out_size, void* d_ws, size_t ws_size,
                              hipStream_t stream) {
  const float* img   = (const float*)d_in[0];
  const float* grid  = (const float*)d_in[1];
  const float* refp  = (const float*)d_in[2];
  const float* Wv    = (const float*)d_in[3];
  const float* bv    = (const float*)d_in[4];
  const float* Woff  = (const float*)d_in[5];
  const float* boff  = (const float*)d_in[6];
  const float* Wattn = (const float*)d_in[7];
  const float* battn = (const float*)d_in[8];
  const float* Wout  = (const float*)d_in[9];
  const float* bout  = (const float*)d_in[10];
  float* out = (float*)d_out;

  char* ws = (char*)d_ws;
  const size_t SZ = (size_t)kM * kC * 2;  // 24.576 MB per bf16 [M][C] buffer
  ushort* feat   = (ushort*)(ws);
  ushort* warped = (ushort*)(ws + SZ);
  ushort* vbuf   = (ushort*)(ws + 2 * SZ);           // [b][h][q][32] head-major
  float4* samp   = (float4*)(ws + 3 * SZ);           // [b][h][q][4], 24.576 MB
  ushort* WvT    = (ushort*)(ws + 4 * SZ);
  ushort* WoffT  = (ushort*)(ws + 4 * SZ + 131072);
  ushort* WattnT = (ushort*)(ws + 4 * SZ + 131072 + 32768);
  ushort* WoutT  = (ushort*)(ws + 4 * SZ + 131072 + 32768 + 16384);
  ushort* aggb   = warped;  // warped is dead after gemm<0>; reuse for agg

  k_wt<<<(65536 + 255) / 256, 256, 0, stream>>>(Wv, WvT, 256, 256);
  k_wt<<<(16384 + 255) / 256, 256, 0, stream>>>(Woff, WoffT, 256, 64);
  k_wt<<<(8192 + 255) / 256, 256, 0, stream>>>(Wattn, WattnT, 256, 32);
  k_wt<<<(65536 + 255) / 256, 256, 0, stream>>>(Wout, WoutT, 256, 256);

  k_transpose<<<dim3(63, 4, 12), 256, 0, stream>>>(img, feat);
  k_warp<<<6000, 256, 0, stream>>>(feat, grid, warped);
  k_gemm256<0><<<756, 256, 20480, stream>>>(warped, WvT, bv, vbuf, nullptr, nullptr);
  k_offattn<<<756, 256, 25856, stream>>>(feat, WoffT, WattnT, boff, battn, refp, samp);
  k_sample<<<6048, 256, 0, stream>>>(vbuf, samp, aggb);
  k_gemm256<1><<<756, 256, 20480, stream>>>(aggb, WoutT, bout, nullptr, out, img);
}